// Round 16
// baseline (208.173 us; speedup 1.0000x reference)
//
#include <hip/hip_runtime.h>
#include <hip/hip_bf16.h>

typedef __hip_bfloat16 bf16;
typedef short short8 __attribute__((ext_vector_type(8)));
typedef float floatx4 __attribute__((ext_vector_type(4)));
typedef unsigned short ushort;

#define MFMA __builtin_amdgcn_mfma_f32_16x16x32_bf16

#define BATCH 4
#define SEQ   1024
#define DIM   1024
#define HEADS 16
#define HD    64
#define RS    72    // LDS row stride in shorts

// scores = -(sq_i - 2 q.k + sq_j)*0.125. Analytic max = self-score (dist=0),
// so p = exp(0.25*dot - 0.125*sq_j - 0.125*sq_i) = exp(-dist^2/8) in (0,1]
// is the EXACT softmax numerator — no running max needed.
//
// LESSON (r10, r14): never stage bf16 operands via global scratch — GEMMs
// reading freshly-written cross-XCD stash lines trigger ~14x HBM write
// amplification. Convert during LDS staging from pristine inputs instead.

__device__ __forceinline__ float b2f(ushort u) {
    union { unsigned i; float f; } x; x.i = (unsigned)u << 16; return x.f;
}
__device__ __forceinline__ ushort f2b(float f) {   // RTNE
    union { float f; unsigned i; } x; x.f = f;
    return (ushort)((x.i + 0x7FFFu + ((x.i >> 16) & 1u)) >> 16);
}

// 8 fp32 (two uint4) -> 8 bf16 via hw packed cvt (v_cvt_pk_bf16_f32, RTNE)
__device__ __forceinline__ short8 cvt8(uint4 a, uint4 b) {
    const float* f0 = (const float*)&a;
    const float* f1 = (const float*)&b;
    union { __hip_bfloat162 h; unsigned u; } c0, c1, c2, c3;
    float2 p;
    p.x = f0[0]; p.y = f0[1]; c0.h = __float22bfloat162_rn(p);
    p.x = f0[2]; p.y = f0[3]; c1.h = __float22bfloat162_rn(p);
    p.x = f1[0]; p.y = f1[1]; c2.h = __float22bfloat162_rn(p);
    p.x = f1[2]; p.y = f1[3]; c3.h = __float22bfloat162_rn(p);
    short8 s;
    unsigned* su = (unsigned*)&s;
    su[0] = c0.u; su[1] = c1.u; su[2] = c2.u; su[3] = c3.u;
    return s;
}

// ---------------------------------------------------------------------------
// QV projection GEMM (byte-identical to rounds 13/15).
// C[M=4096,N=1024] = x_f32[M,K] @ W_f32[N,K]^T + bias_f32, packed-cvt staging.
// Fused Q+V: blockIdx.x<16 -> Q bf16 [bh,n,d]; else V^T bf16 [bh,d,n].
// 128x64 tile, BK=64, register double-buffer prefetch, LDS-transposed writes.
// ---------------------------------------------------------------------------
__global__ __launch_bounds__(256)
void gemm_qv(const float* __restrict__ Av,
             const float* __restrict__ W0, const float* __restrict__ b0,
             const float* __restrict__ W1, const float* __restrict__ b1,
             ushort* __restrict__ Qd, ushort* __restrict__ Vd)
{
    __shared__ __align__(16) ushort SMEM[128 * RS + 64 * RS];   // 27 KB
    ushort* Asm = SMEM;
    ushort* Bsm = SMEM + 128 * RS;

    const int t = threadIdx.x;
    const int w = t >> 6, lane = t & 63;
    const int lr = lane & 15, quad = lane >> 4;
    const int isV = (blockIdx.x >= 16);
    const int n0 = (blockIdx.x & 15) * 64;
    const int m0 = blockIdx.y * 128;
    const float* __restrict__ W    = isV ? W1 : W0;
    const float* __restrict__ bias = isV ? b1 : b0;
    const int mw = (w >> 1) * 64, nw = (w & 1) * 32;
    const int ar = t >> 3, ac8 = (t & 7) * 8;

    uint4 apre[8], wpre[4];
    #pragma unroll
    for (int c = 0; c < 4; ++c) {
        const float* ap = Av + (size_t)(m0 + c * 32 + ar) * DIM + ac8;
        apre[2 * c]     = *(const uint4*)ap;
        apre[2 * c + 1] = *(const uint4*)(ap + 4);
    }
    #pragma unroll
    for (int c = 0; c < 2; ++c) {
        const float* wp = W + (size_t)(n0 + c * 32 + ar) * DIM + ac8;
        wpre[2 * c]     = *(const uint4*)wp;
        wpre[2 * c + 1] = *(const uint4*)(wp + 4);
    }

    floatx4 acc[4][2];
    const floatx4 fz = {0.f, 0.f, 0.f, 0.f};
    #pragma unroll
    for (int i = 0; i < 4; ++i)
        #pragma unroll
        for (int j = 0; j < 2; ++j) acc[i][j] = fz;

    for (int kt = 0; kt < 16; ++kt) {
        #pragma unroll
        for (int c = 0; c < 4; ++c)
            *(short8*)&Asm[(c * 32 + ar) * RS + ac8] = cvt8(apre[2 * c], apre[2 * c + 1]);
        #pragma unroll
        for (int c = 0; c < 2; ++c)
            *(short8*)&Bsm[(c * 32 + ar) * RS + ac8] = cvt8(wpre[2 * c], wpre[2 * c + 1]);
        __syncthreads();
        if (kt < 15) {
            const int k0 = (kt + 1) * 64;
            #pragma unroll
            for (int c = 0; c < 4; ++c) {
                const float* ap = Av + (size_t)(m0 + c * 32 + ar) * DIM + k0 + ac8;
                apre[2 * c]     = *(const uint4*)ap;
                apre[2 * c + 1] = *(const uint4*)(ap + 4);
            }
            #pragma unroll
            for (int c = 0; c < 2; ++c) {
                const float* wp = W + (size_t)(n0 + c * 32 + ar) * DIM + k0 + ac8;
                wpre[2 * c]     = *(const uint4*)wp;
                wpre[2 * c + 1] = *(const uint4*)(wp + 4);
            }
        }
        short8 af[4][2], bfx[2][2];
        #pragma unroll
        for (int tm = 0; tm < 4; ++tm)
            #pragma unroll
            for (int ks = 0; ks < 2; ++ks)
                af[tm][ks] = *(const short8*)&Asm[(mw + tm * 16 + lr) * RS + ks * 32 + quad * 8];
        #pragma unroll
        for (int tn = 0; tn < 2; ++tn)
            #pragma unroll
            for (int ks = 0; ks < 2; ++ks)
                bfx[tn][ks] = *(const short8*)&Bsm[(nw + tn * 16 + lr) * RS + ks * 32 + quad * 8];
        #pragma unroll
        for (int tm = 0; tm < 4; ++tm)
            #pragma unroll
            for (int tn = 0; tn < 2; ++tn) {
                acc[tm][tn] = MFMA(af[tm][0], bfx[tn][0], acc[tm][tn], 0, 0, 0);
                acc[tm][tn] = MFMA(af[tm][1], bfx[tn][1], acc[tm][tn], 0, 0, 0);
            }
        __syncthreads();   // also protects SMEM reuse by the epilogue
    }

    // epilogue: D layout col=lane&15, row=quad*4+reg [verified m89/m91]
    const int bb = m0 >> 10, ii0 = m0 & 1023;
    const int head = blockIdx.x & 15;
    const int bh = bb * HEADS + head;
    if (!isV) {
        #pragma unroll
        for (int tn = 0; tn < 2; ++tn) {
            const float bval = bias[n0 + nw + tn * 16 + lr];
            #pragma unroll
            for (int tm = 0; tm < 4; ++tm)
                #pragma unroll
                for (int r = 0; r < 4; ++r)
                    SMEM[(mw + tm * 16 + quad * 4 + r) * 80 + nw + tn * 16 + lr] =
                        f2b(acc[tm][tn][r] + bval);
        }
        __syncthreads();
        #pragma unroll
        for (int it = 0; it < 4; ++it) {
            const int cid = it * 256 + t;
            const int row = cid >> 3, col8 = (cid & 7) * 8;
            *(uint4*)(Qd + ((size_t)bh * SEQ + ii0 + row) * HD + col8) =
                *(const uint4*)&SMEM[row * 80 + col8];
        }
    } else {
        #pragma unroll
        for (int tn = 0; tn < 2; ++tn) {
            const float bval = bias[n0 + nw + tn * 16 + lr];
            #pragma unroll
            for (int tm = 0; tm < 4; ++tm)
                #pragma unroll
                for (int r = 0; r < 4; ++r)
                    SMEM[(nw + tn * 16 + lr) * 144 + mw + tm * 16 + quad * 4 + r] =
                        f2b(acc[tm][tn][r] + bval);
        }
        __syncthreads();
        #pragma unroll
        for (int it = 0; it < 4; ++it) {
            const int cid = it * 256 + t;
            const int row = cid >> 4, col8 = (cid & 15) * 8;
            *(uint4*)(Vd + ((size_t)bh * HD + row) * SEQ + ii0 + col8) =
                *(const uint4*)&SMEM[row * 144 + col8];
        }
    }
}

// ---------------------------------------------------------------------------
// Output GEMM: out[M=4096,N=1024] = Oh_bf16[M,K] @ Wo_f32[N,K]^T + bo, fp32.
// NEW: 64x64 tile -> 1024 blocks (4/CU) for latency hiding (was 512, 2/CU,
// occupancy 17.5%). 4 waves, each 32x32 (2x2 MFMA frags). LDS 18.4 KB.
// Single-pass LDS-transpose epilogue, full-line float4 writes.
// ---------------------------------------------------------------------------
__global__ __launch_bounds__(256)
void gemm_out(const ushort* __restrict__ A,
              const float* __restrict__ W, const float* __restrict__ bias,
              float* __restrict__ Fd)
{
    __shared__ __align__(16) ushort SMEM[64 * RS + 64 * RS];   // 18432 B
    ushort* Asm = SMEM;
    ushort* Bsm = SMEM + 64 * RS;

    const int t = threadIdx.x;
    const int w = t >> 6, lane = t & 63;
    const int lr = lane & 15, quad = lane >> 4;
    const int n0 = blockIdx.x * 64;           // gridDim.x = 16
    const int m0 = blockIdx.y * 64;           // gridDim.y = 64
    const int mw = (w >> 1) * 32, nw = (w & 1) * 32;
    const int ar = t >> 3, ac8 = (t & 7) * 8;

    uint4 apre[2], wpre[4];
    #pragma unroll
    for (int c = 0; c < 2; ++c)
        apre[c] = *(const uint4*)(A + (size_t)(m0 + c * 32 + ar) * DIM + ac8);
    #pragma unroll
    for (int c = 0; c < 2; ++c) {
        const float* wp = W + (size_t)(n0 + c * 32 + ar) * DIM + ac8;
        wpre[2 * c]     = *(const uint4*)wp;
        wpre[2 * c + 1] = *(const uint4*)(wp + 4);
    }

    floatx4 acc[2][2];
    const floatx4 fz = {0.f, 0.f, 0.f, 0.f};
    #pragma unroll
    for (int i = 0; i < 2; ++i)
        #pragma unroll
        for (int j = 0; j < 2; ++j) acc[i][j] = fz;

    for (int kt = 0; kt < 16; ++kt) {
        #pragma unroll
        for (int c = 0; c < 2; ++c)
            *(uint4*)&Asm[(c * 32 + ar) * RS + ac8] = apre[c];
        #pragma unroll
        for (int c = 0; c < 2; ++c)
            *(short8*)&Bsm[(c * 32 + ar) * RS + ac8] = cvt8(wpre[2 * c], wpre[2 * c + 1]);
        __syncthreads();
        if (kt < 15) {
            const int k0 = (kt + 1) * 64;
            #pragma unroll
            for (int c = 0; c < 2; ++c)
                apre[c] = *(const uint4*)(A + (size_t)(m0 + c * 32 + ar) * DIM + k0 + ac8);
            #pragma unroll
            for (int c = 0; c < 2; ++c) {
                const float* wp = W + (size_t)(n0 + c * 32 + ar) * DIM + k0 + ac8;
                wpre[2 * c]     = *(const uint4*)wp;
                wpre[2 * c + 1] = *(const uint4*)(wp + 4);
            }
        }
        short8 af[2][2], bfx[2][2];
        #pragma unroll
        for (int tm = 0; tm < 2; ++tm)
            #pragma unroll
            for (int ks = 0; ks < 2; ++ks)
                af[tm][ks] = *(const short8*)&Asm[(mw + tm * 16 + lr) * RS + ks * 32 + quad * 8];
        #pragma unroll
        for (int tn = 0; tn < 2; ++tn)
            #pragma unroll
            for (int ks = 0; ks < 2; ++ks)
                bfx[tn][ks] = *(const short8*)&Bsm[(nw + tn * 16 + lr) * RS + ks * 32 + quad * 8];
        #pragma unroll
        for (int tm = 0; tm < 2; ++tm)
            #pragma unroll
            for (int tn = 0; tn < 2; ++tn) {
                acc[tm][tn] = MFMA(af[tm][0], bfx[tn][0], acc[tm][tn], 0, 0, 0);
                acc[tm][tn] = MFMA(af[tm][1], bfx[tn][1], acc[tm][tn], 0, 0, 0);
            }
        __syncthreads();   // also protects SMEM reuse by the epilogue
    }

    // epilogue: single-pass LDS transpose (64 fp32 rows, stride 68 = 17.4 KB)
    float* TF = (float*)SMEM;
    #pragma unroll
    for (int tn = 0; tn < 2; ++tn) {
        const float bval = bias[n0 + nw + tn * 16 + lr];
        #pragma unroll
        for (int tm = 0; tm < 2; ++tm)
            #pragma unroll
            for (int r = 0; r < 4; ++r)
                TF[(mw + tm * 16 + quad * 4 + r) * 68 + nw + tn * 16 + lr] =
                    acc[tm][tn][r] + bval;
    }
    __syncthreads();
    #pragma unroll
    for (int it = 0; it < 4; ++it) {
        const int cid = it * 256 + t;               // 0..1023
        const int row = cid >> 4, c4 = (cid & 15) * 4;
        *(float4*)(Fd + (size_t)(m0 + row) * DIM + n0 + c4) =
            *(const float4*)&TF[row * 68 + c4];
    }
}

// ---------------------------------------------------------------------------
// MFMA flash L2-attention (byte-identical to round 15). i-tile 128, 512
// blocks, XCD swizzle bh=id&63. Q bf16 [bh][n][64], Vt bf16 [bh][d][n].
// O bf16 [b][n][h*d].
// ---------------------------------------------------------------------------
__global__ __launch_bounds__(256)
void attn_mfma(const ushort* __restrict__ Q, const ushort* __restrict__ Vt,
               ushort* __restrict__ O)
{
    __shared__ __align__(16) ushort Ps[128 * RS];
    __shared__ __align__(16) ushort Ks[64 * RS];
    __shared__ __align__(16) ushort Vs[64 * RS];
    __shared__ float sqq[128], sqk[64];

    const int t = threadIdx.x;
    const int w = t >> 6, lane = t & 63;
    const int lr = lane & 15, quad = lane >> 4;
    const int id = blockIdx.x;
    const int bh = id & 63;
    const int i0 = (id >> 6) * 128;
    const ushort* __restrict__ Qp = Q  + (size_t)bh * SEQ * HD;
    const ushort* __restrict__ Vp = Vt + (size_t)bh * HD * SEQ;

    const int sr = t >> 3, sc8 = (t & 7) * 8;

    #pragma unroll
    for (int it = 0; it < 4; ++it) {
        const int cid = it * 256 + t;
        const int r = cid >> 3, c8 = (cid & 7) * 8;
        *(uint4*)&Ps[r * RS + c8] = *(const uint4*)(Qp + (size_t)(i0 + r) * HD + c8);
    }
    __syncthreads();

    {
        const int qsub = quad & 1, half = quad >> 1;
        const int qr = w * 32 + qsub * 16 + lr, ch = half * 32;
        float s = 0.f;
        #pragma unroll
        for (int cc = 0; cc < 4; ++cc) {
            uint4 k = *(const uint4*)&Ps[qr * RS + ch + cc * 8];
            const ushort* u = (const ushort*)&k;
            #pragma unroll
            for (int e = 0; e < 8; ++e) { float f = b2f(u[e]); s += f * f; }
        }
        s += __shfl_xor(s, 32);
        if (half == 0) sqq[qr] = s;
    }
    __syncthreads();

    short8 qa[2][2];
    #pragma unroll
    for (int tm = 0; tm < 2; ++tm)
        #pragma unroll
        for (int ks = 0; ks < 2; ++ks)
            qa[tm][ks] = *(const short8*)&Ps[(w * 32 + tm * 16 + lr) * RS + ks * 32 + quad * 8];
    float sqi[2][4];
    #pragma unroll
    for (int tm = 0; tm < 2; ++tm)
        #pragma unroll
        for (int r = 0; r < 4; ++r)
            sqi[tm][r] = sqq[w * 32 + tm * 16 + quad * 4 + r];

    floatx4 oacc[2][4];
    const floatx4 fz = {0.f, 0.f, 0.f, 0.f};
    float lrow[2][4] = {};
    #pragma unroll
    for (int tm = 0; tm < 2; ++tm)
        #pragma unroll
        for (int td = 0; td < 4; ++td) oacc[tm][td] = fz;

    for (int jt = 0; jt < 16; ++jt) {
        const int j0 = jt * 64;
        __syncthreads();
        #pragma unroll
        for (int it = 0; it < 2; ++it) {
            const int r = it * 32 + sr;
            *(uint4*)&Ks[r * RS + sc8] = *(const uint4*)(Qp + (size_t)(j0 + r) * HD + sc8);
            *(uint4*)&Vs[r * RS + sc8] = *(const uint4*)(Vp + (size_t)r * SEQ + j0 + sc8);
        }
        __syncthreads();

        {
            const int jr = w * 16 + lr, ch = quad * 16;
            uint4 k1 = *(const uint4*)&Ks[jr * RS + ch];
            uint4 k2 = *(const uint4*)&Ks[jr * RS + ch + 8];
            const ushort* u1 = (const ushort*)&k1;
            const ushort* u2 = (const ushort*)&k2;
            float s = 0.f;
            #pragma unroll
            for (int cc = 0; cc < 8; ++cc) {
                float f1 = b2f(u1[cc]), f2 = b2f(u2[cc]);
                s += f1 * f1 + f2 * f2;
            }
            s += __shfl_xor(s, 16);
            s += __shfl_xor(s, 32);
            if (quad == 0) sqk[jr] = s;
        }
        __syncthreads();

        float sq4[4];
        #pragma unroll
        for (int tn = 0; tn < 4; ++tn) sq4[tn] = sqk[tn * 16 + lr];

        short8 kb[4][2];
        #pragma unroll
        for (int tn = 0; tn < 4; ++tn)
            #pragma unroll
            for (int ks = 0; ks < 2; ++ks)
                kb[tn][ks] = *(const short8*)&Ks[(tn * 16 + lr) * RS + ks * 32 + quad * 8];

        #pragma unroll
        for (int tm = 0; tm < 2; ++tm) {
            floatx4 sacc[4];
            #pragma unroll
            for (int tn = 0; tn < 4; ++tn) {
                floatx4 a = MFMA(qa[tm][0], kb[tn][0], fz, 0, 0, 0);
                sacc[tn]  = MFMA(qa[tm][1], kb[tn][1], a, 0, 0, 0);
            }
            float sc[4][4];
            #pragma unroll
            for (int tn = 0; tn < 4; ++tn) {
                const float msq = -0.125f * sq4[tn];
                #pragma unroll
                for (int r = 0; r < 4; ++r)
                    sc[tn][r] = __expf(0.25f * sacc[tn][r] + msq - 0.125f * sqi[tm][r]);
            }
            #pragma unroll
            for (int r = 0; r < 4; ++r)
                lrow[tm][r] += sc[0][r] + sc[1][r] + sc[2][r] + sc[3][r];
            #pragma unroll
            for (int tp = 0; tp < 2; ++tp)
                #pragma unroll
                for (int r = 0; r < 4; ++r) {
                    float2 fp; fp.x = sc[2 * tp][r]; fp.y = sc[2 * tp + 1][r];
                    union { __hip_bfloat162 h; unsigned u; } cv;
                    cv.h = __float22bfloat162_rn(fp);
                    const int rowb = (w * 32 + tm * 16 + quad * 4 + r) * RS + lr;
                    Ps[rowb + (2 * tp) * 16]     = (ushort)(cv.u & 0xffffu);
                    Ps[rowb + (2 * tp + 1) * 16] = (ushort)(cv.u >> 16);
                }
        }
        __syncthreads();   // P stores visible before PV fragment reads

        short8 pa[2][2], vb[4][2];
        #pragma unroll
        for (int tm = 0; tm < 2; ++tm)
            #pragma unroll
            for (int ks = 0; ks < 2; ++ks)
                pa[tm][ks] = *(const short8*)&Ps[(w * 32 + tm * 16 + lr) * RS + ks * 32 + quad * 8];
        #pragma unroll
        for (int td = 0; td < 4; ++td)
            #pragma unroll
            for (int ks = 0; ks < 2; ++ks)
                vb[td][ks] = *(const short8*)&Vs[(td * 16 + lr) * RS + ks * 32 + quad * 8];
        #pragma unroll
        for (int tm = 0; tm < 2; ++tm)
            #pragma unroll
            for (int td = 0; td < 4; ++td) {
                oacc[tm][td] = MFMA(pa[tm][0], vb[td][0], oacc[tm][td], 0, 0, 0);
                oacc[tm][td] = MFMA(pa[tm][1], vb[td][1], oacc[tm][td], 0, 0, 0);
            }
    }

    const int bb = bh >> 4, head = bh & 15;
    #pragma unroll
    for (int tm = 0; tm < 2; ++tm)
        #pragma unroll
        for (int r = 0; r < 4; ++r) {
            float l = lrow[tm][r];
            l += __shfl_xor(l, 1);
            l += __shfl_xor(l, 2);
            l += __shfl_xor(l, 4);
            l += __shfl_xor(l, 8);
            const float inv = 1.f / l;
            const int row = i0 + w * 32 + tm * 16 + quad * 4 + r;
            #pragma unroll
            for (int td = 0; td < 4; ++td) {
                O[(size_t)(bb * SEQ + row) * DIM + head * HD + td * 16 + lr] =
                    f2b(oacc[tm][td][r] * inv);
            }
        }
}

extern "C" void kernel_launch(void* const* d_in, const int* in_sizes, int n_in,
                              void* d_out, int out_size, void* d_ws, size_t ws_size,
                              hipStream_t stream)
{
    const float* x  = (const float*)d_in[0];
    const float* Wq = (const float*)d_in[1];
    const float* bq = (const float*)d_in[2];
    const float* Wv = (const float*)d_in[3];
    const float* bv = (const float*)d_in[4];
    const float* Wo = (const float*)d_in[5];
    const float* bo = (const float*)d_in[6];

    // d_ws (proven 24 MB): Qh 8MB | Vt 8MB | Oh 8MB
    ushort* Qh = (ushort*)d_ws;
    ushort* Vt = Qh + (size_t)BATCH * HEADS * SEQ * HD;
    ushort* Oh = Vt + (size_t)BATCH * HEADS * SEQ * HD;

    gemm_qv<<<dim3(32, 32), 256, 0, stream>>>(x, Wq, bq, Wv, bv, Qh, Vt);
    attn_mfma<<<512, 256, 0, stream>>>(Qh, Vt, Oh);
    gemm_out<<<dim3(16, 64), 256, 0, stream>>>(Oh, Wo, bo, (float*)d_out);
}

// Round 17
// 202.090 us; speedup vs baseline: 1.0301x; 1.0301x over previous
//
#include <hip/hip_runtime.h>
#include <hip/hip_bf16.h>

typedef __hip_bfloat16 bf16;
typedef short short8 __attribute__((ext_vector_type(8)));
typedef float floatx4 __attribute__((ext_vector_type(4)));
typedef unsigned short ushort;

#define MFMA __builtin_amdgcn_mfma_f32_16x16x32_bf16

#define BATCH 4
#define SEQ   1024
#define DIM   1024
#define HEADS 16
#define HD    64
#define RS    72    // LDS row stride in shorts

// scores = -(sq_i - 2 q.k + sq_j)*0.125. Analytic max = self-score (dist=0),
// so p = exp(0.25*dot - 0.125*sq_j - 0.125*sq_i) = exp(-dist^2/8) in (0,1]
// is the EXACT softmax numerator — no running max needed.
//
// LESSON (r10, r14): never stage bf16 operands via global scratch — GEMMs
// reading freshly-written cross-XCD stash lines trigger ~14x HBM write
// amplification. Convert during LDS staging from pristine inputs instead.
// LESSON (r12, r16): register prefetch & smaller tiles don't beat the
// compiler on the 2-barrier K-loop; the ~50us/kernel floor is the
// source-level latency plateau (cf. m97/m131-m141).

__device__ __forceinline__ float b2f(ushort u) {
    union { unsigned i; float f; } x; x.i = (unsigned)u << 16; return x.f;
}
__device__ __forceinline__ ushort f2b(float f) {   // RTNE
    union { float f; unsigned i; } x; x.f = f;
    return (ushort)((x.i + 0x7FFFu + ((x.i >> 16) & 1u)) >> 16);
}

// 8 fp32 (two uint4) -> 8 bf16 via hw packed cvt (v_cvt_pk_bf16_f32, RTNE)
__device__ __forceinline__ short8 cvt8(uint4 a, uint4 b) {
    const float* f0 = (const float*)&a;
    const float* f1 = (const float*)&b;
    union { __hip_bfloat162 h; unsigned u; } c0, c1, c2, c3;
    float2 p;
    p.x = f0[0]; p.y = f0[1]; c0.h = __float22bfloat162_rn(p);
    p.x = f0[2]; p.y = f0[3]; c1.h = __float22bfloat162_rn(p);
    p.x = f1[0]; p.y = f1[1]; c2.h = __float22bfloat162_rn(p);
    p.x = f1[2]; p.y = f1[3]; c3.h = __float22bfloat162_rn(p);
    short8 s;
    unsigned* su = (unsigned*)&s;
    su[0] = c0.u; su[1] = c1.u; su[2] = c2.u; su[3] = c3.u;
    return s;
}

// ---------------------------------------------------------------------------
// MFMA GEMM core (round-13/15 proven). C = A @ W_f32^T + bias_f32.
// 128x64 tile, BK=64, register double-buffer prefetch, packed-cvt staging.
// OUT=0: A = x fp32 (converted during staging). Fused Q+V: blockIdx.x<16 ->
//        Q bf16 [bh,n,d]; else V^T bf16 [bh,d,n]. LDS-transposed writes.
// OUT=1: A = Oh bf16; LDS-transpose epilogue, full-line fp32 writes.
// ---------------------------------------------------------------------------
template<int OUT>
__global__ __launch_bounds__(256)
void gemm_core(const void* __restrict__ Av,
               const float* __restrict__ W0, const float* __restrict__ b0,
               const float* __restrict__ W1, const float* __restrict__ b1,
               ushort* __restrict__ Qd, ushort* __restrict__ Vd,
               float* __restrict__ Fd)
{
    constexpr int AF32 = (OUT == 0) ? 1 : 0;
    __shared__ __align__(16) ushort SMEM[128 * RS + 64 * RS];   // 27 KB
    ushort* Asm = SMEM;
    ushort* Bsm = SMEM + 128 * RS;

    const int t = threadIdx.x;
    const int w = t >> 6, lane = t & 63;
    const int lr = lane & 15, quad = lane >> 4;
    const int isV = (!OUT) && (blockIdx.x >= 16);
    const int n0 = (blockIdx.x & 15) * 64;
    const int m0 = blockIdx.y * 128;
    const float* __restrict__ W    = isV ? W1 : W0;
    const float* __restrict__ bias = isV ? b1 : b0;
    const int mw = (w >> 1) * 64, nw = (w & 1) * 32;
    const int ar = t >> 3, ac8 = (t & 7) * 8;

    uint4 apre[AF32 ? 8 : 4], wpre[4];
    #pragma unroll
    for (int c = 0; c < 4; ++c) {
        if (AF32) {
            const float* ap = (const float*)Av + (size_t)(m0 + c * 32 + ar) * DIM + ac8;
            apre[2 * c]     = *(const uint4*)ap;
            apre[2 * c + 1] = *(const uint4*)(ap + 4);
        } else {
            apre[c] = *(const uint4*)((const ushort*)Av + (size_t)(m0 + c * 32 + ar) * DIM + ac8);
        }
    }
    #pragma unroll
    for (int c = 0; c < 2; ++c) {
        const float* wp = W + (size_t)(n0 + c * 32 + ar) * DIM + ac8;
        wpre[2 * c]     = *(const uint4*)wp;
        wpre[2 * c + 1] = *(const uint4*)(wp + 4);
    }

    floatx4 acc[4][2];
    const floatx4 fz = {0.f, 0.f, 0.f, 0.f};
    #pragma unroll
    for (int i = 0; i < 4; ++i)
        #pragma unroll
        for (int j = 0; j < 2; ++j) acc[i][j] = fz;

    for (int kt = 0; kt < 16; ++kt) {
        #pragma unroll
        for (int c = 0; c < 4; ++c) {
            if (AF32) {
                *(short8*)&Asm[(c * 32 + ar) * RS + ac8] = cvt8(apre[2 * c], apre[2 * c + 1]);
            } else {
                *(uint4*)&Asm[(c * 32 + ar) * RS + ac8] = apre[c];
            }
        }
        #pragma unroll
        for (int c = 0; c < 2; ++c)
            *(short8*)&Bsm[(c * 32 + ar) * RS + ac8] = cvt8(wpre[2 * c], wpre[2 * c + 1]);
        __syncthreads();
        if (kt < 15) {
            const int k0 = (kt + 1) * 64;
            #pragma unroll
            for (int c = 0; c < 4; ++c) {
                if (AF32) {
                    const float* ap = (const float*)Av + (size_t)(m0 + c * 32 + ar) * DIM + k0 + ac8;
                    apre[2 * c]     = *(const uint4*)ap;
                    apre[2 * c + 1] = *(const uint4*)(ap + 4);
                } else {
                    apre[c] = *(const uint4*)((const ushort*)Av + (size_t)(m0 + c * 32 + ar) * DIM + k0 + ac8);
                }
            }
            #pragma unroll
            for (int c = 0; c < 2; ++c) {
                const float* wp = W + (size_t)(n0 + c * 32 + ar) * DIM + k0 + ac8;
                wpre[2 * c]     = *(const uint4*)wp;
                wpre[2 * c + 1] = *(const uint4*)(wp + 4);
            }
        }
        short8 af[4][2], bfx[2][2];
        #pragma unroll
        for (int tm = 0; tm < 4; ++tm)
            #pragma unroll
            for (int ks = 0; ks < 2; ++ks)
                af[tm][ks] = *(const short8*)&Asm[(mw + tm * 16 + lr) * RS + ks * 32 + quad * 8];
        #pragma unroll
        for (int tn = 0; tn < 2; ++tn)
            #pragma unroll
            for (int ks = 0; ks < 2; ++ks)
                bfx[tn][ks] = *(const short8*)&Bsm[(nw + tn * 16 + lr) * RS + ks * 32 + quad * 8];
        #pragma unroll
        for (int tm = 0; tm < 4; ++tm)
            #pragma unroll
            for (int tn = 0; tn < 2; ++tn) {
                acc[tm][tn] = MFMA(af[tm][0], bfx[tn][0], acc[tm][tn], 0, 0, 0);
                acc[tm][tn] = MFMA(af[tm][1], bfx[tn][1], acc[tm][tn], 0, 0, 0);
            }
        __syncthreads();   // also protects SMEM reuse by the epilogue
    }

    // epilogue: D layout col=lane&15, row=quad*4+reg [verified m89/m91]
    if (OUT) {
        float* TF = (float*)SMEM;
        #pragma unroll
        for (int pass = 0; pass < 2; ++pass) {
            __syncthreads();
            if ((w >> 1) == pass) {
                #pragma unroll
                for (int tn = 0; tn < 2; ++tn) {
                    const float bval = bias[n0 + nw + tn * 16 + lr];
                    #pragma unroll
                    for (int tm = 0; tm < 4; ++tm)
                        #pragma unroll
                        for (int r = 0; r < 4; ++r)
                            TF[(tm * 16 + quad * 4 + r) * 68 + nw + tn * 16 + lr] =
                                acc[tm][tn][r] + bval;
                }
            }
            __syncthreads();
            #pragma unroll
            for (int it = 0; it < 4; ++it) {
                const int cid = it * 256 + t;
                const int row = cid >> 4, c4 = (cid & 15) * 4;
                *(float4*)(Fd + (size_t)(m0 + pass * 64 + row) * DIM + n0 + c4) =
                    *(const float4*)&TF[row * 68 + c4];
            }
        }
        return;
    }

    const int bb = m0 >> 10, ii0 = m0 & 1023;
    const int head = blockIdx.x & 15;
    const int bh = bb * HEADS + head;
    if (!isV) {
        #pragma unroll
        for (int tn = 0; tn < 2; ++tn) {
            const float bval = bias[n0 + nw + tn * 16 + lr];
            #pragma unroll
            for (int tm = 0; tm < 4; ++tm)
                #pragma unroll
                for (int r = 0; r < 4; ++r)
                    SMEM[(mw + tm * 16 + quad * 4 + r) * 80 + nw + tn * 16 + lr] =
                        f2b(acc[tm][tn][r] + bval);
        }
        __syncthreads();
        #pragma unroll
        for (int it = 0; it < 4; ++it) {
            const int cid = it * 256 + t;
            const int row = cid >> 3, col8 = (cid & 7) * 8;
            *(uint4*)(Qd + ((size_t)bh * SEQ + ii0 + row) * HD + col8) =
                *(const uint4*)&SMEM[row * 80 + col8];
        }
    } else {
        #pragma unroll
        for (int tn = 0; tn < 2; ++tn) {
            const float bval = bias[n0 + nw + tn * 16 + lr];
            #pragma unroll
            for (int tm = 0; tm < 4; ++tm)
                #pragma unroll
                for (int r = 0; r < 4; ++r)
                    SMEM[(nw + tn * 16 + lr) * 144 + mw + tm * 16 + quad * 4 + r] =
                        f2b(acc[tm][tn][r] + bval);
        }
        __syncthreads();
        #pragma unroll
        for (int it = 0; it < 4; ++it) {
            const int cid = it * 256 + t;
            const int row = cid >> 4, col8 = (cid & 15) * 8;
            *(uint4*)(Vd + ((size_t)bh * HD + row) * SEQ + ii0 + col8) =
                *(const uint4*)&SMEM[row * 144 + col8];
        }
    }
}

// ---------------------------------------------------------------------------
// MFMA flash L2-attention, i-tile 128 (round-15 proven). 512 blocks, XCD
// swizzle bh=id&63 (8 i-blocks per bh on one XCD -> K/V re-reads served from
// that XCD's L2; FETCH 69->9.4 MB). Q bf16 [bh][n][64], Vt bf16 [bh][d][n].
// O bf16 [b][n][h*d].
// ---------------------------------------------------------------------------
__global__ __launch_bounds__(256)
void attn_mfma(const ushort* __restrict__ Q, const ushort* __restrict__ Vt,
               ushort* __restrict__ O)
{
    __shared__ __align__(16) ushort Ps[128 * RS];   // Q stage, then P [i][j]
    __shared__ __align__(16) ushort Ks[64 * RS];
    __shared__ __align__(16) ushort Vs[64 * RS];
    __shared__ float sqq[128], sqk[64];

    const int t = threadIdx.x;
    const int w = t >> 6, lane = t & 63;
    const int lr = lane & 15, quad = lane >> 4;
    const int id = blockIdx.x;
    const int bh = id & 63;            // 512 blocks: 8 i-blocks x 64 bh
    const int i0 = (id >> 6) * 128;
    const ushort* __restrict__ Qp = Q  + (size_t)bh * SEQ * HD;
    const ushort* __restrict__ Vp = Vt + (size_t)bh * HD * SEQ;

    const int sr = t >> 3, sc8 = (t & 7) * 8;

    #pragma unroll
    for (int it = 0; it < 4; ++it) {
        const int cid = it * 256 + t;
        const int r = cid >> 3, c8 = (cid & 7) * 8;
        *(uint4*)&Ps[r * RS + c8] = *(const uint4*)(Qp + (size_t)(i0 + r) * HD + c8);
    }
    __syncthreads();

    {
        const int qsub = quad & 1, half = quad >> 1;
        const int qr = w * 32 + qsub * 16 + lr, ch = half * 32;
        float s = 0.f;
        #pragma unroll
        for (int cc = 0; cc < 4; ++cc) {
            uint4 k = *(const uint4*)&Ps[qr * RS + ch + cc * 8];
            const ushort* u = (const ushort*)&k;
            #pragma unroll
            for (int e = 0; e < 8; ++e) { float f = b2f(u[e]); s += f * f; }
        }
        s += __shfl_xor(s, 32);
        if (half == 0) sqq[qr] = s;
    }
    __syncthreads();

    short8 qa[2][2];
    #pragma unroll
    for (int tm = 0; tm < 2; ++tm)
        #pragma unroll
        for (int ks = 0; ks < 2; ++ks)
            qa[tm][ks] = *(const short8*)&Ps[(w * 32 + tm * 16 + lr) * RS + ks * 32 + quad * 8];
    float sqi[2][4];
    #pragma unroll
    for (int tm = 0; tm < 2; ++tm)
        #pragma unroll
        for (int r = 0; r < 4; ++r)
            sqi[tm][r] = sqq[w * 32 + tm * 16 + quad * 4 + r];

    floatx4 oacc[2][4];
    const floatx4 fz = {0.f, 0.f, 0.f, 0.f};
    float lrow[2][4] = {};
    #pragma unroll
    for (int tm = 0; tm < 2; ++tm)
        #pragma unroll
        for (int td = 0; td < 4; ++td) oacc[tm][td] = fz;

    for (int jt = 0; jt < 16; ++jt) {
        const int j0 = jt * 64;
        __syncthreads();
        #pragma unroll
        for (int it = 0; it < 2; ++it) {
            const int r = it * 32 + sr;
            *(uint4*)&Ks[r * RS + sc8] = *(const uint4*)(Qp + (size_t)(j0 + r) * HD + sc8);
            *(uint4*)&Vs[r * RS + sc8] = *(const uint4*)(Vp + (size_t)r * SEQ + j0 + sc8);
        }
        __syncthreads();

        {
            const int jr = w * 16 + lr, ch = quad * 16;
            uint4 k1 = *(const uint4*)&Ks[jr * RS + ch];
            uint4 k2 = *(const uint4*)&Ks[jr * RS + ch + 8];
            const ushort* u1 = (const ushort*)&k1;
            const ushort* u2 = (const ushort*)&k2;
            float s = 0.f;
            #pragma unroll
            for (int cc = 0; cc < 8; ++cc) {
                float f1 = b2f(u1[cc]), f2 = b2f(u2[cc]);
                s += f1 * f1 + f2 * f2;
            }
            s += __shfl_xor(s, 16);
            s += __shfl_xor(s, 32);
            if (quad == 0) sqk[jr] = s;
        }
        __syncthreads();

        float sq4[4];
        #pragma unroll
        for (int tn = 0; tn < 4; ++tn) sq4[tn] = sqk[tn * 16 + lr];

        short8 kb[4][2];
        #pragma unroll
        for (int tn = 0; tn < 4; ++tn)
            #pragma unroll
            for (int ks = 0; ks < 2; ++ks)
                kb[tn][ks] = *(const short8*)&Ks[(tn * 16 + lr) * RS + ks * 32 + quad * 8];

        #pragma unroll
        for (int tm = 0; tm < 2; ++tm) {
            floatx4 sacc[4];
            #pragma unroll
            for (int tn = 0; tn < 4; ++tn) {
                floatx4 a = MFMA(qa[tm][0], kb[tn][0], fz, 0, 0, 0);
                sacc[tn]  = MFMA(qa[tm][1], kb[tn][1], a, 0, 0, 0);
            }
            float sc[4][4];
            #pragma unroll
            for (int tn = 0; tn < 4; ++tn) {
                const float msq = -0.125f * sq4[tn];
                #pragma unroll
                for (int r = 0; r < 4; ++r)
                    sc[tn][r] = __expf(0.25f * sacc[tn][r] + msq - 0.125f * sqi[tm][r]);
            }
            #pragma unroll
            for (int r = 0; r < 4; ++r)
                lrow[tm][r] += sc[0][r] + sc[1][r] + sc[2][r] + sc[3][r];
            #pragma unroll
            for (int tp = 0; tp < 2; ++tp)
                #pragma unroll
                for (int r = 0; r < 4; ++r) {
                    float2 fp; fp.x = sc[2 * tp][r]; fp.y = sc[2 * tp + 1][r];
                    union { __hip_bfloat162 h; unsigned u; } cv;
                    cv.h = __float22bfloat162_rn(fp);
                    const int rowb = (w * 32 + tm * 16 + quad * 4 + r) * RS + lr;
                    Ps[rowb + (2 * tp) * 16]     = (ushort)(cv.u & 0xffffu);
                    Ps[rowb + (2 * tp + 1) * 16] = (ushort)(cv.u >> 16);
                }
        }
        __syncthreads();   // P stores visible before PV fragment reads

        short8 pa[2][2], vb[4][2];
        #pragma unroll
        for (int tm = 0; tm < 2; ++tm)
            #pragma unroll
            for (int ks = 0; ks < 2; ++ks)
                pa[tm][ks] = *(const short8*)&Ps[(w * 32 + tm * 16 + lr) * RS + ks * 32 + quad * 8];
        #pragma unroll
        for (int td = 0; td < 4; ++td)
            #pragma unroll
            for (int ks = 0; ks < 2; ++ks)
                vb[td][ks] = *(const short8*)&Vs[(td * 16 + lr) * RS + ks * 32 + quad * 8];
        #pragma unroll
        for (int tm = 0; tm < 2; ++tm)
            #pragma unroll
            for (int td = 0; td < 4; ++td) {
                oacc[tm][td] = MFMA(pa[tm][0], vb[td][0], oacc[tm][td], 0, 0, 0);
                oacc[tm][td] = MFMA(pa[tm][1], vb[td][1], oacc[tm][td], 0, 0, 0);
            }
    }

    const int bb = bh >> 4, head = bh & 15;
    #pragma unroll
    for (int tm = 0; tm < 2; ++tm)
        #pragma unroll
        for (int r = 0; r < 4; ++r) {
            float l = lrow[tm][r];
            l += __shfl_xor(l, 1);
            l += __shfl_xor(l, 2);
            l += __shfl_xor(l, 4);
            l += __shfl_xor(l, 8);
            const float inv = 1.f / l;
            const int row = i0 + w * 32 + tm * 16 + quad * 4 + r;
            #pragma unroll
            for (int td = 0; td < 4; ++td) {
                O[(size_t)(bb * SEQ + row) * DIM + head * HD + td * 16 + lr] =
                    f2b(oacc[tm][td][r] * inv);
            }
        }
}

extern "C" void kernel_launch(void* const* d_in, const int* in_sizes, int n_in,
                              void* d_out, int out_size, void* d_ws, size_t ws_size,
                              hipStream_t stream)
{
    const float* x  = (const float*)d_in[0];
    const float* Wq = (const float*)d_in[1];
    const float* bq = (const float*)d_in[2];
    const float* Wv = (const float*)d_in[3];
    const float* bv = (const float*)d_in[4];
    const float* Wo = (const float*)d_in[5];
    const float* bo = (const float*)d_in[6];

    // d_ws (proven 24 MB): Qh 8MB | Vt 8MB | Oh 8MB
    ushort* Qh = (ushort*)d_ws;
    ushort* Vt = Qh + (size_t)BATCH * HEADS * SEQ * HD;
    ushort* Oh = Vt + (size_t)BATCH * HEADS * SEQ * HD;

    gemm_core<0><<<dim3(32, 32), 256, 0, stream>>>(x, Wq, bq, Wv, bv, Qh, Vt, nullptr);
    attn_mfma<<<512, 256, 0, stream>>>(Qh, Vt, Oh);
    gemm_core<1><<<dim3(16, 32), 256, 0, stream>>>(Oh, Wo, bo, nullptr, nullptr,
                                                   nullptr, nullptr, (float*)d_out);
}